// Round 7
// baseline (180.985 us; speedup 1.0000x reference)
//
#include <hip/hip_runtime.h>
#include <cstdint>

typedef unsigned short u16;
typedef __attribute__((ext_vector_type(8))) short s16x8;
typedef __attribute__((ext_vector_type(8))) unsigned short u16x8;
typedef __attribute__((ext_vector_type(4))) float f32x4;
typedef __attribute__((ext_vector_type(16))) float f32x16;
typedef __attribute__((ext_vector_type(2))) unsigned uint2v;
typedef __attribute__((ext_vector_type(4))) unsigned uint4v;

__device__ inline u16 f2bf(float f){
  union { float f; uint32_t u; } v; v.f = f;
  uint32_t r = v.u + 0x7fffu + ((v.u >> 16) & 1u);
  return (u16)(r >> 16);
}

__device__ inline f32x4 mfma16(s16x8 a, s16x8 b, f32x4 c){
  return __builtin_amdgcn_mfma_f32_16x16x32_bf16(a, b, c, 0, 0, 0);
}
__device__ inline f32x16 mfma32(s16x8 a, s16x8 b, f32x16 c){
  return __builtin_amdgcn_mfma_f32_32x32x16_bf16(a, b, c, 0, 0, 0);
}
__device__ inline unsigned cvtpk(float a, float b){
  unsigned r;
  asm("v_cvt_pk_bf16_f32 %0, %1, %2" : "=v"(r) : "v"(a), "v"(b));
  return r;
}
__device__ inline float exp2a(float x){
  float r;
  asm("v_exp_f32 %0, %1" : "=v"(r) : "v"(x));
  return r;
}
__device__ inline void glds16(const u16* g, u16* l){
  __builtin_amdgcn_global_load_lds((const __attribute__((address_space(1))) void*)g,
                                   (__attribute__((address_space(3))) void*)l, 16, 0, 0);
}
__device__ inline void glds4(const unsigned* g, unsigned* l){
  __builtin_amdgcn_global_load_lds((const __attribute__((address_space(1))) void*)g,
                                   (__attribute__((address_space(3))) void*)l, 4, 0, 0);
}

// ---------------------------------------------------------------- convert q/k/v to bf16
__global__ __launch_bounds__(256) void convert3_kernel(
    const float* __restrict__ q, const float* __restrict__ k, const float* __restrict__ v,
    u16* __restrict__ qo, u16* __restrict__ ko, u16* __restrict__ vo){
  const float* src = (blockIdx.y == 0) ? q : (blockIdx.y == 1) ? k : v;
  u16* dst = (blockIdx.y == 0) ? qo : (blockIdx.y == 1) ? ko : vo;
  size_t i = ((size_t)blockIdx.x * 256 + threadIdx.x) * 8;
  float4 a = *(const float4*)(src + i);
  float4 b = *(const float4*)(src + i + 4);
  u16x8 o = { f2bf(a.x), f2bf(a.y), f2bf(a.z), f2bf(a.w),
              f2bf(b.x), f2bf(b.y), f2bf(b.z), f2bf(b.w) };
  *(u16x8*)(dst + i) = o;
}

// ---------------------------------------------------------------- transpose+convert weights
__global__ void transw_kernel(
    const float* __restrict__ W0, const float* __restrict__ W1,
    const float* __restrict__ W2, const float* __restrict__ W3,
    u16* __restrict__ T0, u16* __restrict__ T1, u16* __restrict__ T2, u16* __restrict__ T3){
  const float* W = (blockIdx.z == 0) ? W0 : (blockIdx.z == 1) ? W1 : (blockIdx.z == 2) ? W2 : W3;
  u16* T = (blockIdx.z == 0) ? T0 : (blockIdx.z == 1) ? T1 : (blockIdx.z == 2) ? T2 : T3;
  __shared__ float t[32][33];
  int n0 = blockIdx.x * 32, k0 = blockIdx.y * 32;
  int tx = threadIdx.x, ty = threadIdx.y; // (32,8)
  #pragma unroll
  for (int j = 0; j < 4; j++)
    t[ty + j*8][tx] = W[(size_t)(k0 + ty + j*8) * 1024 + n0 + tx];
  __syncthreads();
  #pragma unroll
  for (int j = 0; j < 4; j++)
    T[(size_t)(n0 + ty + j*8) * 1024 + k0 + tx] = f2bf(t[tx][ty + j*8]);
}

// ---------------------------------------------------------------- pack mask to bits
__global__ __launch_bounds__(256) void packmask_kernel(const int* __restrict__ mask,
                                                       unsigned* __restrict__ bits){
  size_t i = (size_t)blockIdx.x * 256 + threadIdx.x;
  int v = mask[i];
  unsigned long long bal = __ballot(v != 0);
  int lane = threadIdx.x & 63;
  if (lane == 0)       bits[i >> 5] = (unsigned)bal;
  else if (lane == 32) bits[i >> 5] = (unsigned)(bal >> 32);
}

// ---------------------------------------------------------------- ctx = market_context @ Wc + bc
__global__ __launch_bounds__(256) void ctx_kernel(const float* __restrict__ mc,
                                                  const float* __restrict__ Wc,
                                                  const float* __restrict__ bc,
                                                  float* __restrict__ ctx){
  int c = threadIdx.x & 63, kk = threadIdx.x >> 6;
  int col = blockIdx.x * 64 + c;
  float a0 = 0.f, a1 = 0.f;
  for (int k = kk * 256; k < kk * 256 + 256; k++){
    float wv = Wc[(size_t)k * 1024 + col];
    a0 += mc[k] * wv;
    a1 += mc[1024 + k] * wv;
  }
  __shared__ float red[2][4][64];
  red[0][kk][c] = a0; red[1][kk][c] = a1;
  __syncthreads();
  if (threadIdx.x < 64){
    int cc = threadIdx.x;
    ctx[blockIdx.x*64 + cc] = red[0][0][cc] + red[0][1][cc] + red[0][2][cc] + red[0][3][cc]
                              + bc[blockIdx.x*64 + cc];
  } else if (threadIdx.x < 128){
    int cc = threadIdx.x - 64;
    ctx[1024 + blockIdx.x*64 + cc] = red[1][0][cc] + red[1][1][cc] + red[1][2][cc] + red[1][3][cc]
                                     + bc[blockIdx.x*64 + cc];
  }
}

// ---------------------------------------------------------------- GEMM: BK=32 double-buffered,
// counted-vmcnt pipeline (never drain in-loop). XCD swizzle keyed on BY (A-panel locality).
struct GemmParams {
  const u16* A0; const u16* A1; const u16* A2; const u16* A3;
  const u16* W0; const u16* W1; const u16* W2; const u16* W3;
  const float* b0; const float* b1; const float* b2;
  const float* ctx;
  u16* outQ; u16* outK; u16* outV; float* outX0; float* outX1;
  int which;
};

__global__ __launch_bounds__(256) void gemm_kernel(GemmParams P){
  int o = blockIdx.x + (blockIdx.y << 3) + (blockIdx.z << 8);
  int xcd = o & 7, j = o >> 3;
  int by = xcd + ((j & 3) << 3);
  int bx = (j >> 2) & 7;
  int bz = j >> 5;

  int z, kbase, nkt;
  const u16* A; const u16* W;
  if (P.which < 0){
    z = bz; kbase = 0; nkt = 32;
    if (z == 0){ A = P.A0; W = P.W0; }
    else if (z == 1){ A = P.A1; W = P.W1; }
    else { A = P.A2; W = P.W2; }
  } else {
    z = 3; kbase = bz * 512; nkt = 16;
    A = P.A3; W = P.W3;
  }
  int m0 = by * 128, n0 = bx * 128;
  // buf b: A at b*8192 (128x32 u16), B at b*8192+4096. Reused (full 32KB) for z=2 transpose.
  __shared__ __align__(16) u16 sm[16384];
  int tid = threadIdx.x, lane = tid & 63, w = tid >> 6;
  int li = lane & 15, lq = lane >> 4;
  int wm = w >> 1, wn = w & 1;
  f32x4 zero = {0.f, 0.f, 0.f, 0.f};
  f32x4 acc[4][4];
  #pragma unroll
  for (int i = 0; i < 4; i++)
    #pragma unroll
    for (int jj = 0; jj < 4; jj++) acc[i][jj] = zero;

  // STAGE: 4 glds16 per wave (2 A + 2 B), lane-linear dest, source col pre-swizzled.
  auto STAGE = [&](int kt, int buf){
    int k0 = kbase + kt * 32;
    u16* Ab = &sm[buf * 8192];
    u16* Bb = &sm[buf * 8192 + 4096];
    #pragma unroll
    for (int i = 0; i < 2; i++){
      int u0 = i * 256 + (w << 6);
      int u = u0 + lane, row = u >> 2, slot = u & 3;
      int scol = (slot ^ ((row >> 1) & 3)) << 3;
      glds16(A + (size_t)(m0 + row) * 1024 + k0 + scol, &Ab[u0 * 8]);
      glds16(W + (size_t)(n0 + row) * 1024 + k0 + scol, &Bb[u0 * 8]);
    }
  };

  STAGE(0, 0);

  for (int kt = 0; kt < nkt; ++kt){
    int cur = kt & 1;
    __builtin_amdgcn_s_barrier();           // A: compute(kt-1) done, buf cur^1 free
    if (kt + 1 < nkt){
      STAGE(kt + 1, cur ^ 1);
      asm volatile("s_waitcnt vmcnt(4)" ::: "memory");  // my 4 loads for buf cur landed
    } else {
      asm volatile("s_waitcnt vmcnt(0)" ::: "memory");
    }
    __builtin_amdgcn_sched_barrier(0);
    __builtin_amdgcn_s_barrier();           // B: everyone's buf-cur data landed
    const u16* Ab = &sm[cur * 8192];
    const u16* Bb = &sm[cur * 8192 + 4096];
    s16x8 af[4], bfr[4];
    #pragma unroll
    for (int mb = 0; mb < 4; mb++){
      int row = wm * 64 + mb * 16 + li;
      af[mb] = *(const s16x8*)&Ab[row * 32 + ((lq ^ ((row >> 1) & 3)) << 3)];
    }
    #pragma unroll
    for (int nb = 0; nb < 4; nb++){
      int row = wn * 64 + nb * 16 + li;
      bfr[nb] = *(const s16x8*)&Bb[row * 32 + ((lq ^ ((row >> 1) & 3)) << 3)];
    }
    __builtin_amdgcn_s_setprio(1);
    #pragma unroll
    for (int mb = 0; mb < 4; mb++)
      #pragma unroll
      for (int nb = 0; nb < 4; nb++)
        acc[mb][nb] = mfma16(af[mb], bfr[nb], acc[mb][nb]);
    __builtin_amdgcn_s_setprio(0);
  }

  if (z == 2){
    const float* bias = P.b2;
    __syncthreads();
    u16* Ot = sm;
    #pragma unroll
    for (int mb = 0; mb < 4; mb++){
      #pragma unroll
      for (int nb = 0; nb < 4; nb++){
        int colL = wn * 64 + nb * 16 + li;
        int rowB = wm * 64 + mb * 16 + lq * 4;
        float bcol = bias[n0 + colL];
        unsigned p01 = cvtpk(acc[mb][nb][0] + bcol, acc[mb][nb][1] + bcol);
        unsigned p23 = cvtpk(acc[mb][nb][2] + bcol, acc[mb][nb][3] + bcol);
        int ba = colL * 256 + ((rowB * 2) ^ ((colL & 7) << 4));
        *(unsigned*)((char*)Ot + ba) = p01;
        *(unsigned*)((char*)Ot + ba + 4) = p23;
      }
    }
    __syncthreads();
    int bq_ = m0 >> 11, srow0 = m0 & 2047;
    #pragma unroll
    for (int i = 0; i < 8; i++){
      int u = i * 256 + tid;
      int colL = u >> 4, sc = u & 15;
      int ba = colL * 256 + ((sc * 16) ^ ((colL & 7) << 4));
      u16x8 vv = *(const u16x8*)((char*)Ot + ba);
      *(u16x8*)(P.outV + (((size_t)(bq_ * 1024 + n0 + colL)) << 11) + srow0 + sc * 8) = vv;
    }
    return;
  }

  if (z == 3){
    float* Xo = (kbase == 0) ? P.outX0 : P.outX1;
    #pragma unroll
    for (int mb = 0; mb < 4; mb++){
      #pragma unroll
      for (int nb = 0; nb < 4; nb++){
        int col = n0 + wn * 64 + nb * 16 + li;
        #pragma unroll
        for (int r = 0; r < 4; r++){
          int row = m0 + wm * 64 + mb * 16 + lq * 4 + r;
          Xo[(size_t)row * 1024 + col] = acc[mb][nb][r];
        }
      }
    }
    return;
  }

  const float* bias = (z == 0) ? P.b0 : P.b1;
  #pragma unroll
  for (int mb = 0; mb < 4; mb++){
    #pragma unroll
    for (int nb = 0; nb < 4; nb++){
      int colL = wn * 64 + nb * 16 + li; int col = n0 + colL;
      float bcol = bias[col];
      #pragma unroll
      for (int r = 0; r < 4; r++){
        int row = m0 + wm * 64 + mb * 16 + lq * 4 + r;
        float v = acc[mb][nb][r] + bcol;
        if (z == 0){
          P.outQ[(size_t)row * 1024 + col] = f2bf(v);
        } else {
          v += P.ctx[(size_t)(row >> 11) * 1024 + col];
          P.outK[(size_t)row * 1024 + col] = f2bf(v);
        }
      }
    }
  }
}

// ---------------------------------------------------------------- flash attention
// grid (16,32) XCD-swizzled; 128 q-rows/block, 4 waves. Counted-vmcnt double-buffer (R6).
// Static softmax; row-sum via MFMA ones-trick (accS) instead of VALU adds.
__global__ __launch_bounds__(256) void attn_kernel(
    const u16* __restrict__ Qg, const u16* __restrict__ Kg, const u16* __restrict__ Vtg,
    const unsigned* __restrict__ mbits, u16* __restrict__ ctx2){
  __shared__ __align__(16) u16 arena[17408];
  int tid = threadIdx.x, lane = tid & 63, w = tid >> 6;
  int l31 = lane & 31, hi = lane >> 5;
  int r7 = l31 & 7;
  int orig = blockIdx.x + (blockIdx.y << 4);
  int swz = (orig & 7) * 64 + (orig >> 3);
  int q0 = (swz & 15) * 128, bh = swz >> 4, b = bh >> 4, h = bh & 15;
  const float CK = 0.18033688011f;  // log2(e)/8
  const float MK = 64.f * CK;       // static max (raw 64 == scaled 8)

  s16x8 qf[4];
  {
    const u16* qp = Qg + (size_t)(b * 2048 + q0 + w * 32 + l31) * 1024 + h * 64 + hi * 8;
    #pragma unroll
    for (int ks = 0; ks < 4; ks++)
      qf[ks] = *(const s16x8*)(qp + ks * 16);
  }
  s16x8 onesf;
  #pragma unroll
  for (int e = 0; e < 8; e++) onesf[e] = (short)0x3F80;  // bf16 1.0

  auto STAGE = [&](int kt, int buf){
    int kv0 = kt * 64;
    u16* Kbuf = &arena[buf * 8192];
    u16* Vbuf = &arena[buf * 8192 + 4096];
    unsigned* Ms = (unsigned*)&arena[16384] + buf * 256;
    #pragma unroll
    for (int i = 0; i < 2; i++){
      int u0 = (w * 2 + i) * 64;
      int u = u0 + lane, row = u >> 3, slot = u & 7;
      int scol = (slot ^ (row & 7)) << 3;
      glds16(Kg + (size_t)(b * 2048 + kv0 + row) * 1024 + h * 64 + scol, &Kbuf[u0 * 8]);
      glds16(Vtg + (((size_t)(bh * 64 + row)) << 11) + kv0 + scol, &Vbuf[u0 * 8]);
    }
    {
      int u = w * 64 + lane;
      glds4(mbits + (size_t)(b * 2048 + q0 + (u >> 1)) * 64 + kt * 2 + (u & 1), Ms + w * 64);
    }
  };

  f32x16 accO[2], accS;
  #pragma unroll
  for (int d = 0; d < 2; d++)
    #pragma unroll
    for (int r = 0; r < 16; r++) accO[d][r] = 0.f;
  #pragma unroll
  for (int r = 0; r < 16; r++) accS[r] = 0.f;

  STAGE(0, 0);

  for (int t = 0; t < 32; ++t){
    int cur = t & 1;
    __builtin_amdgcn_s_barrier();
    if (t < 31){
      STAGE(t + 1, cur ^ 1);
      asm volatile("s_waitcnt vmcnt(5)" ::: "memory");
    } else {
      asm volatile("s_waitcnt vmcnt(0)" ::: "memory");
    }
    __builtin_amdgcn_sched_barrier(0);
    __builtin_amdgcn_s_barrier();
    const u16* Kbuf = &arena[cur * 8192];
    const u16* Vbuf = &arena[cur * 8192 + 4096];
    const unsigned* Ms = (const unsigned*)&arena[16384] + cur * 256;
    int qr = w * 32 + l31;

    // S^T = K · Q
    f32x16 S[2];
    __builtin_amdgcn_s_setprio(1);
    #pragma unroll
    for (int j = 0; j < 2; j++){
      #pragma unroll
      for (int r = 0; r < 16; r++) S[j][r] = 0.f;
      #pragma unroll
      for (int ks = 0; ks < 4; ks++){
        s16x8 kf = *(const s16x8*)&Kbuf[(j * 32 + l31) * 64 + (((ks * 2 + hi) ^ r7) << 3)];
        S[j] = mfma32(kf, qf[ks], S[j]);
      }
    }
    __builtin_amdgcn_s_setprio(0);

    uint2v mw = *(const uint2v*)(Ms + qr * 2);
    unsigned mh0 = mw[0] >> (hi << 2), mh1 = mw[1] >> (hi << 2);
    #pragma unroll
    for (int j = 0; j < 2; j++){
      unsigned mh = j ? mh1 : mh0;
      #pragma unroll
      for (int rg = 0; rg < 16; rg++){
        int pos = (rg & 3) + ((rg >> 2) << 3);
        float pv = exp2a(S[j][rg] * CK - MK);
        S[j][rg] = ((mh >> pos) & 1u) ? pv : 0.f;
      }
    }

    // P -> bf16 B-fragments via cvt_pk + permlane32_swap
    s16x8 pf[4];
    #pragma unroll
    for (int j = 0; j < 2; j++){
      #pragma unroll
      for (int hs = 0; hs < 2; hs++){
        int rb = hs * 8;
        unsigned A0 = cvtpk(S[j][rb + 0], S[j][rb + 1]);
        unsigned A1 = cvtpk(S[j][rb + 2], S[j][rb + 3]);
        unsigned B0 = cvtpk(S[j][rb + 4], S[j][rb + 5]);
        unsigned B1 = cvtpk(S[j][rb + 6], S[j][rb + 7]);
        uint2v r01 = __builtin_amdgcn_permlane32_swap(A0, B0, false, false);
        uint2v r23 = __builtin_amdgcn_permlane32_swap(A1, B1, false, false);
        uint4v uu = { r01[0], r23[0], r01[1], r23[1] };
        pf[j * 2 + hs] = *(s16x8*)&uu;
      }
    }
    // O^T += V^T · P ; row-sum += ones · P (MFMA pipe, replaces VALU adds)
    __builtin_amdgcn_s_setprio(1);
    #pragma unroll
    for (int c = 0; c < 4; c++){
      #pragma unroll
      for (int dh = 0; dh < 2; dh++){
        s16x8 vf = *(const s16x8*)&Vbuf[(dh * 32 + l31) * 64 + (((c * 2 + hi) ^ r7) << 3)];
        accO[dh] = mfma32(vf, pf[c], accO[dh]);
      }
      accS = mfma32(onesf, pf[c], accS);
    }
    __builtin_amdgcn_s_setprio(0);
  }

  __syncthreads();
  float lsum = accS[0];
  float inv = 1.f / lsum;
  u16* Ot = arena;
  int qr = w * 32 + l31;
  #pragma unroll
  for (int dh = 0; dh < 2; dh++){
    #pragma unroll
    for (int rg = 0; rg < 16; rg += 2){
      int dk = dh * 32 + (rg & 3) + ((rg >> 2) << 3) + (hi << 2);
      unsigned pk = cvtpk(accO[dh][rg] * inv, accO[dh][rg + 1] * inv);
      *(unsigned*)&Ot[qr * 64 + (((dk >> 3) ^ (qr & 7)) << 3) + (dk & 7)] = pk;
    }
  }
  __syncthreads();
  #pragma unroll
  for (int i = 0; i < 4; i++){
    int u = i * 256 + tid, row = u >> 3, slot = u & 7;
    u16x8 vv = *(const u16x8*)&Ot[row * 64 + ((slot ^ (row & 7)) << 3)];
    *(u16x8*)(ctx2 + (size_t)(b * 2048 + q0 + row) * 1024 + h * 64 + slot * 8) = vv;
  }
}

// ---------------------------------------------------------------- LayerNorm of (X0 + X1 + query + bo)
__global__ __launch_bounds__(256) void ln_kernel(const float* __restrict__ X0,
                                                 const float* __restrict__ X1,
                                                 const float* __restrict__ qres,
                                                 const float* __restrict__ bo,
                                                 const float* __restrict__ g,
                                                 const float* __restrict__ bb,
                                                 float* __restrict__ out){
  size_t row = blockIdx.x;
  int tid = threadIdx.x;
  float4 a = *(const float4*)(X0 + row * 1024 + tid * 4);
  float4 c = *(const float4*)(X1 + row * 1024 + tid * 4);
  float4 q = *(const float4*)(qres + row * 1024 + tid * 4);
  float4 bv = *(const float4*)(bo + tid * 4);
  float4 v;
  v.x = a.x + c.x + q.x + bv.x;
  v.y = a.y + c.y + q.y + bv.y;
  v.z = a.z + c.z + q.z + bv.z;
  v.w = a.w + c.w + q.w + bv.w;
  float s = v.x + v.y + v.z + v.w;
  float s2 = v.x*v.x + v.y*v.y + v.z*v.z + v.w*v.w;
  #pragma unroll
  for (int o = 1; o < 64; o <<= 1){
    s += __shfl_xor(s, o, 64);
    s2 += __shfl_xor(s2, o, 64);
  }
  __shared__ float rs[4], rs2[4];
  int w = tid >> 6;
  if ((tid & 63) == 0){ rs[w] = s; rs2[w] = s2; }
  __syncthreads();
  s = rs[0] + rs[1] + rs[2] + rs[3];
  s2 = rs2[0] + rs2[1] + rs2[2] + rs2[3];
  float mu = s * (1.f / 1024.f);
  float var = s2 * (1.f / 1024.f) - mu * mu;
  float rstd = rsqrtf(var + 1e-5f);
  float4 gg = *(const float4*)(g + tid * 4);
  float4 bt = *(const float4*)(bb + tid * 4);
  float4 o;
  o.x = (v.x - mu) * rstd * gg.x + bt.x;
  o.y = (v.y - mu) * rstd * gg.y + bt.y;
  o.z = (v.z - mu) * rstd * gg.z + bt.z;
  o.w = (v.w - mu) * rstd * gg.w + bt.w;
  *(float4*)(out + row * 1024 + tid * 4) = o;
}

// ----------------------------------------------------------------
extern "C" void kernel_launch(void* const* d_in, const int* in_sizes, int n_in,
                              void* d_out, int out_size, void* d_ws, size_t ws_size,
                              hipStream_t stream){
  const float* query = (const float*)d_in[0];
  const float* key_  = (const float*)d_in[1];
  const float* value = (const float*)d_in[2];
  const int*   mask  = (const int*)d_in[3];
  const float* mc    = (const float*)d_in[4];
  const float* Wq = (const float*)d_in[5];  const float* bq = (const float*)d_in[6];
  const float* Wk = (const float*)d_in[7];  const float* bk = (const float*)d_in[8];
  const float* Wv = (const float*)d_in[9];  const float* bv = (const float*)d_in[10];
  const float* Wo = (const float*)d_in[11]; const float* bo = (const float*)d_in[12];
  const float* Wc = (const float*)d_in[13]; const float* bc = (const float*)d_in[14];
  const float* lng = (const float*)d_in[15]; const float* lnb = (const float*)d_in[16];
  float* outp = (float*)d_out;
  uint8_t* ws = (uint8_t*)d_ws;
  const size_t MB = (size_t)1 << 20;
  if (ws_size < 58 * MB) return;

  u16* q_bf = (u16*)(ws + 0);         // dead after QKV; reused as ctx2
  u16* k_bf = (u16*)(ws + 8 * MB);
  u16* v_bf = (u16*)(ws + 16 * MB);
  float* X0 = (float*)(ws + 8 * MB);  // overlays k_bf/v_bf (dead after QKV GEMM)
  u16* Qb   = (u16*)(ws + 24 * MB);
  u16* Kb   = (u16*)(ws + 32 * MB);
  float* X1 = (float*)(ws + 32 * MB); // overlays Kb/Vt (dead after attn)
  u16* Vt   = (u16*)(ws + 40 * MB);
  u16* Wqt  = (u16*)(ws + 48 * MB);
  u16* Wkt  = (u16*)(ws + 50 * MB);
  u16* Wvt  = (u16*)(ws + 52 * MB);
  u16* Wot  = (u16*)(ws + 54 * MB);
  unsigned* mbits = (unsigned*)(ws + 56 * MB);
  float* ctxf = (float*)(ws + 57 * MB);
  u16* ctx2 = q_bf;

  convert3_kernel<<<dim3(2048, 3), 256, 0, stream>>>(query, key_, value, q_bf, k_bf, v_bf);
  transw_kernel<<<dim3(32, 32, 4), dim3(32, 8), 0, stream>>>(Wq, Wk, Wv, Wo, Wqt, Wkt, Wvt, Wot);
  packmask_kernel<<<32768, 256, 0, stream>>>(mask, mbits);
  ctx_kernel<<<16, 256, 0, stream>>>(mc, Wc, bc, ctxf);

  GemmParams gp;
  gp.A0 = q_bf; gp.A1 = k_bf; gp.A2 = v_bf; gp.A3 = ctx2;
  gp.W0 = Wqt;  gp.W1 = Wkt;  gp.W2 = Wvt;  gp.W3 = Wot;
  gp.b0 = bq;   gp.b1 = bk;   gp.b2 = bv;
  gp.ctx = ctxf;
  gp.outQ = Qb; gp.outK = Kb; gp.outV = Vt; gp.outX0 = X0; gp.outX1 = X1;
  gp.which = -1;
  gemm_kernel<<<dim3(8, 32, 3), 256, 0, stream>>>(gp);

  attn_kernel<<<dim3(16, 32), 256, 0, stream>>>(Qb, Kb, Vt, mbits, ctx2);

  gp.which = 3;
  gemm_kernel<<<dim3(8, 32, 2), 256, 0, stream>>>(gp);

  ln_kernel<<<4096, 256, 0, stream>>>(X0, X1, query, bo, lng, lnb, outp);
}

// Round 8
// 170.134 us; speedup vs baseline: 1.0638x; 1.0638x over previous
//
#include <hip/hip_runtime.h>
#include <cstdint>

typedef unsigned short u16;
typedef __attribute__((ext_vector_type(8))) short s16x8;
typedef __attribute__((ext_vector_type(8))) unsigned short u16x8;
typedef __attribute__((ext_vector_type(4))) float f32x4;
typedef __attribute__((ext_vector_type(16))) float f32x16;
typedef __attribute__((ext_vector_type(2))) unsigned uint2v;
typedef __attribute__((ext_vector_type(4))) unsigned uint4v;

#define CKF 0.18033688011f  // log2(e)/8, folded into Q projection

__device__ inline u16 f2bf(float f){
  union { float f; uint32_t u; } v; v.f = f;
  uint32_t r = v.u + 0x7fffu + ((v.u >> 16) & 1u);
  return (u16)(r >> 16);
}

__device__ inline f32x4 mfma16(s16x8 a, s16x8 b, f32x4 c){
  return __builtin_amdgcn_mfma_f32_16x16x32_bf16(a, b, c, 0, 0, 0);
}
__device__ inline f32x16 mfma32(s16x8 a, s16x8 b, f32x16 c){
  return __builtin_amdgcn_mfma_f32_32x32x16_bf16(a, b, c, 0, 0, 0);
}
__device__ inline unsigned cvtpk(float a, float b){
  unsigned r;
  asm("v_cvt_pk_bf16_f32 %0, %1, %2" : "=v"(r) : "v"(a), "v"(b));
  return r;
}
__device__ inline float exp2a(float x){
  float r;
  asm("v_exp_f32 %0, %1" : "=v"(r) : "v"(x));
  return r;
}
__device__ inline void glds16(const u16* g, u16* l){
  __builtin_amdgcn_global_load_lds((const __attribute__((address_space(1))) void*)g,
                                   (__attribute__((address_space(3))) void*)l, 16, 0, 0);
}
__device__ inline void glds4(const unsigned* g, unsigned* l){
  __builtin_amdgcn_global_load_lds((const __attribute__((address_space(1))) void*)g,
                                   (__attribute__((address_space(3))) void*)l, 4, 0, 0);
}

// ---------------------------------------------------------------- convert q/k/v to bf16
__global__ __launch_bounds__(256) void convert3_kernel(
    const float* __restrict__ q, const float* __restrict__ k, const float* __restrict__ v,
    u16* __restrict__ qo, u16* __restrict__ ko, u16* __restrict__ vo){
  const float* src = (blockIdx.y == 0) ? q : (blockIdx.y == 1) ? k : v;
  u16* dst = (blockIdx.y == 0) ? qo : (blockIdx.y == 1) ? ko : vo;
  size_t i = ((size_t)blockIdx.x * 256 + threadIdx.x) * 8;
  float4 a = *(const float4*)(src + i);
  float4 b = *(const float4*)(src + i + 4);
  u16x8 o = { f2bf(a.x), f2bf(a.y), f2bf(a.z), f2bf(a.w),
              f2bf(b.x), f2bf(b.y), f2bf(b.z), f2bf(b.w) };
  *(u16x8*)(dst + i) = o;
}

// ---------------------------------------------------------------- transpose+convert weights
__global__ void transw_kernel(
    const float* __restrict__ W0, const float* __restrict__ W1,
    const float* __restrict__ W2, const float* __restrict__ W3,
    u16* __restrict__ T0, u16* __restrict__ T1, u16* __restrict__ T2, u16* __restrict__ T3){
  const float* W = (blockIdx.z == 0) ? W0 : (blockIdx.z == 1) ? W1 : (blockIdx.z == 2) ? W2 : W3;
  u16* T = (blockIdx.z == 0) ? T0 : (blockIdx.z == 1) ? T1 : (blockIdx.z == 2) ? T2 : T3;
  __shared__ float t[32][33];
  int n0 = blockIdx.x * 32, k0 = blockIdx.y * 32;
  int tx = threadIdx.x, ty = threadIdx.y; // (32,8)
  #pragma unroll
  for (int j = 0; j < 4; j++)
    t[ty + j*8][tx] = W[(size_t)(k0 + ty + j*8) * 1024 + n0 + tx];
  __syncthreads();
  #pragma unroll
  for (int j = 0; j < 4; j++)
    T[(size_t)(n0 + ty + j*8) * 1024 + k0 + tx] = f2bf(t[tx][ty + j*8]);
}

// ---------------------------------------------------------------- pack mask to bits
__global__ __launch_bounds__(256) void packmask_kernel(const int* __restrict__ mask,
                                                       unsigned* __restrict__ bits){
  size_t i = (size_t)blockIdx.x * 256 + threadIdx.x;
  int v = mask[i];
  unsigned long long bal = __ballot(v != 0);
  int lane = threadIdx.x & 63;
  if (lane == 0)       bits[i >> 5] = (unsigned)bal;
  else if (lane == 32) bits[i >> 5] = (unsigned)(bal >> 32);
}

// ---------------------------------------------------------------- ctx = market_context @ Wc + bc
__global__ __launch_bounds__(256) void ctx_kernel(const float* __restrict__ mc,
                                                  const float* __restrict__ Wc,
                                                  const float* __restrict__ bc,
                                                  float* __restrict__ ctx){
  int c = threadIdx.x & 63, kk = threadIdx.x >> 6;
  int col = blockIdx.x * 64 + c;
  float a0 = 0.f, a1 = 0.f;
  for (int k = kk * 256; k < kk * 256 + 256; k++){
    float wv = Wc[(size_t)k * 1024 + col];
    a0 += mc[k] * wv;
    a1 += mc[1024 + k] * wv;
  }
  __shared__ float red[2][4][64];
  red[0][kk][c] = a0; red[1][kk][c] = a1;
  __syncthreads();
  if (threadIdx.x < 64){
    int cc = threadIdx.x;
    ctx[blockIdx.x*64 + cc] = red[0][0][cc] + red[0][1][cc] + red[0][2][cc] + red[0][3][cc]
                              + bc[blockIdx.x*64 + cc];
  } else if (threadIdx.x < 128){
    int cc = threadIdx.x - 64;
    ctx[1024 + blockIdx.x*64 + cc] = red[1][0][cc] + red[1][1][cc] + red[1][2][cc] + red[1][3][cc]
                                     + bc[blockIdx.x*64 + cc];
  }
}

// ---------------------------------------------------------------- GEMM: BK=32 dbuf, counted vmcnt,
// unrolled-by-2 (compile-time buffer), precomputed LDS offsets. XCD swizzle keyed on BY.
struct GemmParams {
  const u16* A0; const u16* A1; const u16* A2; const u16* A3;
  const u16* W0; const u16* W1; const u16* W2; const u16* W3;
  const float* b0; const float* b1; const float* b2;
  const float* ctx;
  u16* outQ; u16* outK; u16* outV; float* outX0; float* outX1;
  int which;
};

__global__ __launch_bounds__(256) void gemm_kernel(GemmParams P){
  int o = blockIdx.x + (blockIdx.y << 3) + (blockIdx.z << 8);
  int xcd = o & 7, j = o >> 3;
  int by = xcd + ((j & 3) << 3);
  int bx = (j >> 2) & 7;
  int bz = j >> 5;

  int z, kbase, nkt;
  const u16* A; const u16* W;
  if (P.which < 0){
    z = bz; kbase = 0; nkt = 32;
    if (z == 0){ A = P.A0; W = P.W0; }
    else if (z == 1){ A = P.A1; W = P.W1; }
    else { A = P.A2; W = P.W2; }
  } else {
    z = 3; kbase = bz * 512; nkt = 16;
    A = P.A3; W = P.W3;
  }
  int m0 = by * 128, n0 = bx * 128;
  __shared__ __align__(16) u16 sm[16384];
  int tid = threadIdx.x, lane = tid & 63, w = tid >> 6;
  int li = lane & 15, lq = lane >> 4;
  int wm = w >> 1, wn = w & 1;
  f32x4 zero = {0.f, 0.f, 0.f, 0.f};
  f32x4 acc[4][4];
  #pragma unroll
  for (int i = 0; i < 4; i++)
    #pragma unroll
    for (int jj = 0; jj < 4; jj++) acc[i][jj] = zero;

  // staging source pointers (advance 32 u16 per kt); scol identical for both row groups
  int scolS = ((lane & 3) ^ ((lane >> 3) & 3)) << 3;
  int row0 = w * 16 + (lane >> 2);       // i=0 rows
  const u16* aS0 = A + (size_t)(m0 + row0) * 1024 + kbase + scolS;
  const u16* aS1 = aS0 + (size_t)64 * 1024;
  const u16* bS0 = W + (size_t)(n0 + row0) * 1024 + kbase + scolS;
  const u16* bS1 = bS0 + (size_t)64 * 1024;
  int aD0 = (w * 64) * 8, aD1 = (256 + w * 64) * 8;  // u16 dest offsets (wave-uniform)

  // LDS read byte offsets (lane-varying, loop-invariant)
  int aOff[4], bOff[4];
  #pragma unroll
  for (int mb = 0; mb < 4; mb++){
    int row = wm * 64 + mb * 16 + li;
    aOff[mb] = (row * 32 + ((lq ^ ((row >> 1) & 3)) << 3)) * 2;
  }
  #pragma unroll
  for (int nb = 0; nb < 4; nb++){
    int row = wn * 64 + nb * 16 + li;
    bOff[nb] = 8192 + (row * 32 + ((lq ^ ((row >> 1) & 3)) << 3)) * 2;
  }

  auto STAGE = [&](int ct){
    u16* Ab = &sm[ct * 8192];
    u16* Bb = &sm[ct * 8192 + 4096];
    glds16(aS0, Ab + aD0);
    glds16(aS1, Ab + aD1);
    glds16(bS0, Bb + aD0);
    glds16(bS1, Bb + aD1);
  };
  auto ADV = [&](){ aS0 += 32; aS1 += 32; bS0 += 32; bS1 += 32; };

  auto KITER = [&](int kt, int ct){
    __builtin_amdgcn_s_barrier();
    if (kt + 1 < nkt){
      STAGE(ct ^ 1); ADV();
      asm volatile("s_waitcnt vmcnt(4)" ::: "memory");
    } else {
      asm volatile("s_waitcnt vmcnt(0)" ::: "memory");
    }
    __builtin_amdgcn_sched_barrier(0);
    __builtin_amdgcn_s_barrier();
    const char* base = (const char*)sm + ct * 16384;
    s16x8 af[4], bfr[4];
    #pragma unroll
    for (int mb = 0; mb < 4; mb++) af[mb] = *(const s16x8*)(base + aOff[mb]);
    #pragma unroll
    for (int nb = 0; nb < 4; nb++) bfr[nb] = *(const s16x8*)(base + bOff[nb]);
    __builtin_amdgcn_s_setprio(1);
    #pragma unroll
    for (int mb = 0; mb < 4; mb++)
      #pragma unroll
      for (int nb = 0; nb < 4; nb++)
        acc[mb][nb] = mfma16(af[mb], bfr[nb], acc[mb][nb]);
    __builtin_amdgcn_s_setprio(0);
  };

  STAGE(0); ADV();
  for (int kt = 0; kt < nkt; kt += 2){
    KITER(kt, 0);
    KITER(kt + 1, 1);
  }

  if (z == 2){
    const float* bias = P.b2;
    __syncthreads();
    u16* Ot = sm;
    #pragma unroll
    for (int mb = 0; mb < 4; mb++){
      #pragma unroll
      for (int nb = 0; nb < 4; nb++){
        int colL = wn * 64 + nb * 16 + li;
        int rowB = wm * 64 + mb * 16 + lq * 4;
        float bcol = bias[n0 + colL];
        unsigned p01 = cvtpk(acc[mb][nb][0] + bcol, acc[mb][nb][1] + bcol);
        unsigned p23 = cvtpk(acc[mb][nb][2] + bcol, acc[mb][nb][3] + bcol);
        int ba = colL * 256 + ((rowB * 2) ^ ((colL & 7) << 4));
        *(unsigned*)((char*)Ot + ba) = p01;
        *(unsigned*)((char*)Ot + ba + 4) = p23;
      }
    }
    __syncthreads();
    int bq_ = m0 >> 11, srow0 = m0 & 2047;
    #pragma unroll
    for (int i = 0; i < 8; i++){
      int u = i * 256 + tid;
      int colL = u >> 4, sc = u & 15;
      int ba = colL * 256 + ((sc * 16) ^ ((colL & 7) << 4));
      u16x8 vv = *(const u16x8*)((char*)Ot + ba);
      *(u16x8*)(P.outV + (((size_t)(bq_ * 1024 + n0 + colL)) << 11) + srow0 + sc * 8) = vv;
    }
    return;
  }

  if (z == 3){
    float* Xo = (kbase == 0) ? P.outX0 : P.outX1;
    #pragma unroll
    for (int mb = 0; mb < 4; mb++){
      #pragma unroll
      for (int nb = 0; nb < 4; nb++){
        int col = n0 + wn * 64 + nb * 16 + li;
        #pragma unroll
        for (int r = 0; r < 4; r++){
          int row = m0 + wm * 64 + mb * 16 + lq * 4 + r;
          Xo[(size_t)row * 1024 + col] = acc[mb][nb][r];
        }
      }
    }
    return;
  }

  const float* bias = (z == 0) ? P.b0 : P.b1;
  #pragma unroll
  for (int mb = 0; mb < 4; mb++){
    #pragma unroll
    for (int nb = 0; nb < 4; nb++){
      int colL = wn * 64 + nb * 16 + li; int col = n0 + colL;
      float bcol = bias[col];
      #pragma unroll
      for (int r = 0; r < 4; r++){
        int row = m0 + wm * 64 + mb * 16 + lq * 4 + r;
        float v = acc[mb][nb][r] + bcol;
        if (z == 0){
          P.outQ[(size_t)row * 1024 + col] = f2bf(v * CKF);  // fold softmax scale into Q
        } else {
          v += P.ctx[(size_t)(row >> 11) * 1024 + col];
          P.outK[(size_t)row * 1024 + col] = f2bf(v);
        }
      }
    }
  }
}

// ---------------------------------------------------------------- flash attention
// grid (16,32) XCD-swizzled; 128 q-rows/block, 4 waves. Counted-vmcnt dbuf, unrolled-by-2,
// precomputed LDS offsets. Scale folded into Q; p = exp2(S) raw (2^M cancels in num/den).
__global__ __launch_bounds__(256) void attn_kernel(
    const u16* __restrict__ Qg, const u16* __restrict__ Kg, const u16* __restrict__ Vtg,
    const unsigned* __restrict__ mbits, u16* __restrict__ ctx2){
  __shared__ __align__(16) u16 arena[17408];
  int tid = threadIdx.x, lane = tid & 63, w = tid >> 6;
  int l31 = lane & 31, hi = lane >> 5;
  int r7 = l31 & 7;
  int orig = blockIdx.x + (blockIdx.y << 4);
  int swz = (orig & 7) * 64 + (orig >> 3);
  int q0 = (swz & 15) * 128, bh = swz >> 4, b = bh >> 4, h = bh & 15;

  s16x8 qf[4];
  {
    const u16* qp = Qg + (size_t)(b * 2048 + q0 + w * 32 + l31) * 1024 + h * 64 + hi * 8;
    #pragma unroll
    for (int ks = 0; ks < 4; ks++)
      qf[ks] = *(const s16x8*)(qp + ks * 16);
  }
  s16x8 onesf;
  #pragma unroll
  for (int e = 0; e < 8; e++) onesf[e] = (short)0x3F80;  // bf16 1.0
  f32x16 ZERO;
  #pragma unroll
  for (int r = 0; r < 16; r++) ZERO[r] = 0.f;

  // staging source pointers (same scol for both row groups: row&7 == lane>>3)
  int scolS = ((lane & 7) ^ (lane >> 3)) << 3;
  int rowS = w * 16 + (lane >> 3);
  const u16* kS0 = Kg + (size_t)(b * 2048 + rowS) * 1024 + h * 64 + scolS;
  const u16* kS1 = kS0 + (size_t)8 * 1024;
  const u16* vS0 = Vtg + (((size_t)(bh * 64 + rowS)) << 11) + scolS;
  const u16* vS1 = vS0 + ((size_t)8 << 11);
  int um = w * 64 + lane;
  const unsigned* mS = mbits + (size_t)(b * 2048 + q0 + (um >> 1)) * 64 + (um & 1);
  int kD0 = w * 1024, kD1 = w * 1024 + 512;  // wave-uniform dest offsets (u16)

  // LDS read byte offsets (lane-varying, loop-invariant)
  int qr = w * 32 + l31;
  int koff[2][4], voff[2][4];
  #pragma unroll
  for (int jj = 0; jj < 2; jj++)
    #pragma unroll
    for (int ks = 0; ks < 4; ks++){
      koff[jj][ks] = ((jj * 32 + l31) * 64 + (((ks * 2 + hi) ^ r7) << 3)) * 2;
      voff[jj][ks] = 8192 + ((jj * 32 + l31) * 64 + (((ks * 2 + hi) ^ r7) << 3)) * 2;
    }
  int mB = 32768 + qr * 8;

  auto STAGE = [&](int ct){
    u16* dst = &arena[ct * 8192];
    glds16(kS0, dst + kD0);
    glds16(kS1, dst + kD1);
    glds16(vS0, dst + 4096 + kD0);
    glds16(vS1, dst + 4096 + kD1);
    glds4(mS, (unsigned*)&arena[16384] + ct * 256 + w * 64);
  };
  auto ADV = [&](){
    kS0 += (size_t)64 * 1024; kS1 += (size_t)64 * 1024;
    vS0 += 64; vS1 += 64; mS += 2;
  };

  f32x16 accO[2], accS;
  #pragma unroll
  for (int d = 0; d < 2; d++) accO[d] = ZERO;
  accS = ZERO;

  STAGE(0); ADV();

  auto ITER = [&](int t, int ct){
    __builtin_amdgcn_s_barrier();
    if (t < 31){
      STAGE(ct ^ 1); ADV();
      asm volatile("s_waitcnt vmcnt(5)" ::: "memory");
    } else {
      asm volatile("s_waitcnt vmcnt(0)" ::: "memory");
    }
    __builtin_amdgcn_sched_barrier(0);
    __builtin_amdgcn_s_barrier();
    const char* base = (const char*)arena + ct * 16384;

    // S^T = K · Q  (Q pre-scaled by log2(e)/8)
    f32x16 S[2];
    __builtin_amdgcn_s_setprio(1);
    #pragma unroll
    for (int jj = 0; jj < 2; jj++){
      S[jj] = ZERO;
      #pragma unroll
      for (int ks = 0; ks < 4; ks++){
        s16x8 kf = *(const s16x8*)(base + koff[jj][ks]);
        S[jj] = mfma32(kf, qf[ks], S[jj]);
      }
    }
    __builtin_amdgcn_s_setprio(0);

    uint2v mw = *(const uint2v*)((const char*)arena + ct * 1024 + mB);
    unsigned mh0 = mw[0] >> (hi << 2), mh1 = mw[1] >> (hi << 2);
    #pragma unroll
    for (int jj = 0; jj < 2; jj++){
      unsigned mh = jj ? mh1 : mh0;
      #pragma unroll
      for (int rg = 0; rg < 16; rg++){
        int pos = (rg & 3) + ((rg >> 2) << 3);
        float pv = exp2a(S[jj][rg]);          // no FMA: scale folded into Q, no max-sub
        S[jj][rg] = ((mh >> pos) & 1u) ? pv : 0.f;
      }
    }

    // P -> bf16 B-fragments via cvt_pk + permlane32_swap
    s16x8 pf[4];
    #pragma unroll
    for (int jj = 0; jj < 2; jj++){
      #pragma unroll
      for (int hs = 0; hs < 2; hs++){
        int rb = hs * 8;
        unsigned A0 = cvtpk(S[jj][rb + 0], S[jj][rb + 1]);
        unsigned A1 = cvtpk(S[jj][rb + 2], S[jj][rb + 3]);
        unsigned B0 = cvtpk(S[jj][rb + 4], S[jj][rb + 5]);
        unsigned B1 = cvtpk(S[jj][rb + 6], S[jj][rb + 7]);
        uint2v r01 = __builtin_amdgcn_permlane32_swap(A0, B0, false, false);
        uint2v r23 = __builtin_amdgcn_permlane32_swap(A1, B1, false, false);
        uint4v uu = { r01[0], r23[0], r01[1], r23[1] };
        pf[jj * 2 + hs] = *(s16x8*)&uu;
      }
    }
    // O^T += V^T · P ; row-sum via ones-MFMA
    __builtin_amdgcn_s_setprio(1);
    #pragma unroll
    for (int c = 0; c < 4; c++){
      #pragma unroll
      for (int dh = 0; dh < 2; dh++){
        s16x8 vf = *(const s16x8*)(base + voff[dh][c]);
        accO[dh] = mfma32(vf, pf[c], accO[dh]);
      }
      accS = mfma32(onesf, pf[c], accS);
    }
    __builtin_amdgcn_s_setprio(0);
  };

  for (int t = 0; t < 32; t += 2){
    ITER(t, 0);
    ITER(t + 1, 1);
  }

  __syncthreads();
  float lsum = accS[0];
  float inv = 1.f / lsum;
  u16* Ot = arena;
  #pragma unroll
  for (int dh = 0; dh < 2; dh++){
    #pragma unroll
    for (int rg = 0; rg < 16; rg += 2){
      int dk = dh * 32 + (rg & 3) + ((rg >> 2) << 3) + (hi << 2);
      unsigned pk = cvtpk(accO[dh][rg] * inv, accO[dh][rg + 1] * inv);
      *(unsigned*)&Ot[qr * 64 + (((dk >> 3) ^ (qr & 7)) << 3) + (dk & 7)] = pk;
    }
  }
  __syncthreads();
  #pragma unroll
  for (int i = 0; i < 4; i++){
    int u = i * 256 + tid, row = u >> 3, slot = u & 7;
    u16x8 vv = *(const u16x8*)&Ot[row * 64 + ((slot ^ (row & 7)) << 3)];
    *(u16x8*)(ctx2 + (size_t)(b * 2048 + q0 + row) * 1024 + h * 64 + slot * 8) = vv;
  }
}

// ---------------------------------------------------------------- LayerNorm of (X0 + X1 + query + bo)
__global__ __launch_bounds__(256) void ln_kernel(const float* __restrict__ X0,
                                                 const float* __restrict__ X1,
                                                 const float* __restrict__ qres,
                                                 const float* __restrict__ bo,
                                                 const float* __restrict__ g,
                                                 const float* __restrict__ bb,
                                                 float* __restrict__ out){
  size_t row = blockIdx.x;
  int tid = threadIdx.x;
  float4 a = *(const float4*)(X0 + row * 1024 + tid * 4);
  float4 c = *(const float4*)(X1 + row * 1024 + tid * 4);
  float4 q = *(const float4*)(qres + row * 1024 + tid * 4);
  float4 bv = *(const float4*)(bo + tid * 4);
  float4 v;
  v.x = a.x + c.x + q.x + bv.x;
  v.y = a.y + c.y + q.y + bv.y;
  v.z = a.z + c.z + q.z + bv.z;
  v.w = a.w + c.w + q.w + bv.w;
  float s = v.x + v.y + v.z + v.w;
  float s2 = v.x*v.x + v.y*v.y + v.z*v.z + v.w*v.w;
  #pragma unroll
  for (int o = 1; o < 64; o <<= 1){
    s += __shfl_xor(s, o, 64);
    s2 += __shfl_xor(s2, o, 64);
  }
  __shared__ float rs[4], rs2[4];
  int w = tid >> 6;
  if ((tid & 63) == 0){ rs[w] = s; rs2[w] = s2; }
  __syncthreads();
  s = rs[0] + rs[1] + rs[2] + rs[3];
  s2 = rs2[0] + rs2[1] + rs2[2] + rs2[3];
  float mu = s * (1.f / 1024.f);
  float var = s2 * (1.f / 1024.f) - mu * mu;
  float rstd = rsqrtf(var + 1e-5f);
  float4 gg = *(const float4*)(g + tid * 4);
  float4 bt = *(const float4*)(bb + tid * 4);
  float4 o;
  o.x = (v.x - mu) * rstd * gg.x + bt.x;
  o.y = (v.y - mu) * rstd * gg.y + bt.y;
  o.z = (v.z - mu) * rstd * gg.z + bt.z;
  o.w = (v.w - mu) * rstd * gg.w + bt.w;
  *(float4*)(out + row * 1024 + tid * 4) = o;
}

// ----------------------------------------------------------------
extern "C" void kernel_launch(void* const* d_in, const int* in_sizes, int n_in,
                              void* d_out, int out_size, void* d_ws, size_t ws_size,
                              hipStream_t stream){
  const float* query = (const float*)d_in[0];
  const float* key_  = (const float*)d_in[1];
  const float* value = (const float*)d_in[2];
  const int*   mask  = (const int*)d_in[3];
  const float* mc    = (const float*)d_in[4];
  const float* Wq = (const float*)d_in[5];  const float* bq = (const float*)d_in[6];
  const float* Wk = (const float*)d_in[7];  const float* bk = (const float*)d_in[8];
  const float* Wv = (const float*)d_in[9];  const float* bv = (const float*)d_in[10];
  const float* Wo = (const float*)d_in[11]; const float* bo = (const float*)d_in[12];
  const float* Wc = (const float*)d_in[13]; const float* bc = (const float*)d_in[14];
  const float* lng = (const float*)d_in[15]; const float* lnb = (const float*)d_in[16];
  float* outp = (float*)d_out;
  uint8_t* ws = (uint8_t*)d_ws;
  const size_t MB = (size_t)1 << 20;
  if (ws_size < 58 * MB) return;

  u16* q_bf = (u16*)(ws + 0);         // dead after QKV; reused as ctx2
  u16* k_bf = (u16*)(ws + 8 * MB);
  u16* v_bf = (u16*)(ws + 16 * MB);
  float* X0 = (float*)(ws + 8 * MB);  // overlays k_bf/v_bf (dead after QKV GEMM)
  u16* Qb   = (u16*)(ws + 24 * MB);
  u16* Kb   = (u16*)(ws + 32 * MB);
  float* X1 = (float*)(ws + 32 * MB); // overlays Kb/Vt (dead after attn)
  u16* Vt   = (u16*)(ws + 40 * MB);
  u16* Wqt  = (u16*)(ws + 48 * MB);
  u16* Wkt  = (u16*)(ws + 50 * MB);
  u16* Wvt  = (u16*)(ws + 52 * MB);
  u16* Wot  = (u16*)(ws + 54 * MB);
  unsigned* mbits = (unsigned*)(ws + 56 * MB);
  float* ctxf = (float*)(ws + 57 * MB);
  u16* ctx2 = q_bf;

  convert3_kernel<<<dim3(2048, 3), 256, 0, stream>>>(query, key_, value, q_bf, k_bf, v_bf);
  transw_kernel<<<dim3(32, 32, 4), dim3(32, 8), 0, stream>>>(Wq, Wk, Wv, Wo, Wqt, Wkt, Wvt, Wot);
  packmask_kernel<<<32768, 256, 0, stream>>>(mask, mbits);
  ctx_kernel<<<16, 256, 0, stream>>>(mc, Wc, bc, ctxf);

  GemmParams gp;
  gp.A0 = q_bf; gp.A1 = k_bf; gp.A2 = v_bf; gp.A3 = ctx2;
  gp.W0 = Wqt;  gp.W1 = Wkt;  gp.W2 = Wvt;  gp.W3 = Wot;
  gp.b0 = bq;   gp.b1 = bk;   gp.b2 = bv;
  gp.ctx = ctxf;
  gp.outQ = Qb; gp.outK = Kb; gp.outV = Vt; gp.outX0 = X0; gp.outX1 = X1;
  gp.which = -1;
  gemm_kernel<<<dim3(8, 32, 3), 256, 0, stream>>>(gp);

  attn_kernel<<<dim3(16, 32), 256, 0, stream>>>(Qb, Kb, Vt, mbits, ctx2);

  gp.which = 3;
  gemm_kernel<<<dim3(8, 32, 2), 256, 0, stream>>>(gp);

  ln_kernel<<<4096, 256, 0, stream>>>(X0, X1, query, bo, lng, lnb, outp);
}